// Round 5
// baseline (354.858 us; speedup 1.0000x reference)
//
#include <hip/hip_runtime.h>

#define F_IN 256
#define F_OUT 64
#define SHIFT 10          // bin width 1024 nodes
#define NBINS_MAX 64      // supports N <= 65536
#define CAP 96            // LDS entries per bin per block (batch max ~80)
#define BATCH 2048        // edges per block in pass1

typedef __attribute__((ext_vector_type(8))) short short8;
typedef __attribute__((ext_vector_type(4))) float f32x4;

// ---------------------------------------------------------------------------
// bf16 helpers. hi = truncated bf16, lo = RNE bf16 of exact residual.
// ---------------------------------------------------------------------------
__device__ inline unsigned short f2bf_rne(float f) {
    unsigned u = __float_as_uint(f);
    return (unsigned short)((u + 0x7fffu + ((u >> 16) & 1u)) >> 16);
}
__device__ inline float trunc_res(float f) {
    return f - __uint_as_float(__float_as_uint(f) & 0xFFFF0000u);
}
__device__ inline float bf_lo(unsigned u) { return __uint_as_float(u << 16); }
__device__ inline float bf_hi(unsigned u) { return __uint_as_float(u & 0xFFFF0000u); }
__device__ inline short8 pack_hi(float4 a, float4 b) {
    union { unsigned u[4]; short8 s; } r;
    r.u[0] = (__float_as_uint(a.x) >> 16) | (__float_as_uint(a.y) & 0xFFFF0000u);
    r.u[1] = (__float_as_uint(a.z) >> 16) | (__float_as_uint(a.w) & 0xFFFF0000u);
    r.u[2] = (__float_as_uint(b.x) >> 16) | (__float_as_uint(b.y) & 0xFFFF0000u);
    r.u[3] = (__float_as_uint(b.z) >> 16) | (__float_as_uint(b.w) & 0xFFFF0000u);
    return r.s;
}
__device__ inline short8 pack_lo(float4 a, float4 b) {
    union { unsigned u[4]; short8 s; } r;
    r.u[0] = f2bf_rne(trunc_res(a.x)) | ((unsigned)f2bf_rne(trunc_res(a.y)) << 16);
    r.u[1] = f2bf_rne(trunc_res(a.z)) | ((unsigned)f2bf_rne(trunc_res(a.w)) << 16);
    r.u[2] = f2bf_rne(trunc_res(b.x)) | ((unsigned)f2bf_rne(trunc_res(b.y)) << 16);
    r.u[3] = f2bf_rne(trunc_res(b.z)) | ((unsigned)f2bf_rne(trunc_res(b.w)) << 16);
    return r.s;
}

// ---------------------------------------------------------------------------
// K1: bin 2048 edges/block by dst>>SHIFT via LDS, single histogram + single
// wave-parallel flush (contiguous ~340B bursts). Overflow (slot>=CAP,
// ~P(Poisson(42)>96), effectively never) falls back to per-edge append.
// ---------------------------------------------------------------------------
__global__ __launch_bounds__(256, 2) void bin_pass1(const int* __restrict__ adj,
                                                    uint2* __restrict__ staging,
                                                    int* __restrict__ cursorRel,
                                                    int E, int nbins, int maxBin) {
    __shared__ uint2 buf[NBINS_MAX][CAP];  // 48 KB
    __shared__ int cnt[NBINS_MAX];
    const int tid = threadIdx.x;
    for (int b = tid; b < NBINS_MAX; b += 256) cnt[b] = 0;
    __syncthreads();

    const int e0 = blockIdx.x * BATCH;
    const int e1 = min(e0 + BATCH, E);
    const bool al4 = ((E & 3) == 0);

#pragma unroll
    for (int half = 0; half < 2; half++) {
        int e = e0 + half * 1024 + tid * 4;
        int ss[4], dd[4];
        int nv = 0;
        if (e < e1) {
            if (al4 && e + 4 <= e1) {
                int4 s4 = *(const int4*)&adj[e];
                int4 d4 = *(const int4*)&adj[E + e];
                ss[0] = s4.x; ss[1] = s4.y; ss[2] = s4.z; ss[3] = s4.w;
                dd[0] = d4.x; dd[1] = d4.y; dd[2] = d4.z; dd[3] = d4.w;
                nv = 4;
            } else {
                for (int k = 0; k < 4 && e + k < e1; k++) {
                    ss[k] = adj[e + k];
                    dd[k] = adj[E + e + k];
                    nv++;
                }
            }
        }
        for (int j = 0; j < nv; j++) {
            int b = dd[j] >> SHIFT;
            int slot = atomicAdd(&cnt[b], 1);
            uint2 ent = make_uint2((unsigned)ss[j], (unsigned)dd[j]);
            if (slot < CAP) {
                buf[b][slot] = ent;
            } else {  // overflow: direct global append (rare, correct)
                int pos = atomicAdd(&cursorRel[b], 1);
                if (pos < maxBin) staging[(size_t)b * maxBin + pos] = ent;
            }
        }
    }
    __syncthreads();

    // wave-parallel flush: wave w handles bins w, w+4, ...
    const int wv = tid >> 6, ln = tid & 63;
    for (int b = wv; b < nbins; b += 4) {
        int c = cnt[b];
        int stored = min(c, CAP);
        int base = 0;
        if (ln == 0 && stored > 0) base = atomicAdd(&cursorRel[b], stored);
        base = __shfl(base, 0, 64);
        for (int i = ln; i < stored; i += 64) {
            int pos = base + i;
            if (pos < maxBin) staging[(size_t)b * maxBin + pos] = buf[b][i];
        }
    }
}

// ---------------------------------------------------------------------------
// K2: one block per bin. Histogram staged dsts -> block scan -> write rowOff
// (segment starts), curg (scatter cursors, = rowOff copy), dinv.
// ---------------------------------------------------------------------------
__global__ __launch_bounds__(256) void scan_bins(const uint2* __restrict__ staging,
                                                 const int* __restrict__ cursorRel,
                                                 int* __restrict__ rowOff,
                                                 int* __restrict__ curg,
                                                 float* __restrict__ dinv,
                                                 int N, int E, int maxBin, int nbins) {
    __shared__ int deg[1024];
    __shared__ int cur[1024];
    __shared__ int wsum[4];
    __shared__ int baseSh;
    const int b = blockIdx.x;
    const int tid = threadIdx.x;
    const int nb0 = b << SHIFT;
    const int nn = min(1024, N - nb0);
    const int segCnt = min(cursorRel[b], maxBin);
    const uint2* seg = staging + (size_t)b * maxBin;

    if (tid < 64) {  // base = edges in bins before this one
        int v = (tid < b) ? min(cursorRel[tid], maxBin) : 0;
        for (int d = 1; d < 64; d <<= 1) v += __shfl_xor(v, d, 64);
        if (tid == 0) baseSh = v;
    }
    for (int j = tid; j < 1024; j += 256) deg[j] = 0;
    __syncthreads();
    const int base = baseSh;

    for (int i = tid; i < segCnt; i += 256) {
        uint2 e = seg[i];
        atomicAdd(&deg[(int)e.y - nb0], 1);
    }
    __syncthreads();

    const int j0 = tid * 4;
    const int d0 = deg[j0], d1 = deg[j0 + 1], d2 = deg[j0 + 2], d3 = deg[j0 + 3];
    const int s = d0 + d1 + d2 + d3;
    const int lane = tid & 63, w = tid >> 6;
    int incl = s;
    for (int d = 1; d < 64; d <<= 1) {
        int t = __shfl_up(incl, d, 64);
        if (lane >= d) incl += t;
    }
    if (lane == 63) wsum[w] = incl;
    __syncthreads();
    int wofs = 0;
    for (int k = 0; k < 3; k++) if (k < w) wofs += wsum[k];
    int ex = base + wofs + incl - s;
    cur[j0] = ex;
    cur[j0 + 1] = ex + d0;
    cur[j0 + 2] = ex + d0 + d1;
    cur[j0 + 3] = ex + d0 + d1 + d2;
    __syncthreads();

    for (int j = tid; j < nn; j += 256) {
        int v = cur[j];
        rowOff[nb0 + j] = v;
        curg[nb0 + j] = v;
        dinv[nb0 + j] = rsqrtf((float)deg[j] + 1.0f);
    }
    if (b == nbins - 1 && tid == 0) rowOff[N] = E;
}

// ---------------------------------------------------------------------------
// K3: parallel scatter, 8 blocks/bin. Global atomics on curg (~294 G/s
// ceiling -> ~3 us for 800K); csr writes stay within each bin's ~65KB
// window, which is hot in L2 while its 8 blocks run -> writeback ~ footprint.
// ---------------------------------------------------------------------------
__global__ __launch_bounds__(256) void scatter_csr(const uint2* __restrict__ staging,
                                                   const int* __restrict__ cursorRel,
                                                   int* __restrict__ curg,
                                                   int* __restrict__ csr,
                                                   int maxBin, int P) {
    const int b = blockIdx.x / P;
    const int p = blockIdx.x - b * P;
    const int segCnt = min(cursorRel[b], maxBin);
    const uint2* seg = staging + (size_t)b * maxBin;
    for (int i = p * 256 + threadIdx.x; i < segCnt; i += P * 256) {
        uint2 e = seg[i];
        int pos = atomicAdd(&curg[(int)e.y], 1);
        csr[pos] = (int)e.x;
    }
}

// ---------------------------------------------------------------------------
// K4: g(bf16) = dinv[n] * (x @ W) via bf16 MFMA, x = hi+lo split.
// 512-thread blocks, 16 nodes/wave (3125 waves -> ~12-16 waves/CU TLP),
// W staged once per 128 nodes into B-fragment-major LDS (u32-packed pairs).
// ---------------------------------------------------------------------------
__global__ __launch_bounds__(512, 4) void gemm_mfma(const float* __restrict__ x,
                                                    const float* __restrict__ W,
                                                    const float* __restrict__ dinv,
                                                    unsigned* __restrict__ gu, int N) {
    __shared__ unsigned Wf[32 * 64 * 4];  // 32 KB: [kchunk][n][4 x u32(bf16x2)]
    for (int p = threadIdx.x; p < (F_IN / 2) * F_OUT; p += 512) {
        int kp = p >> 6;  // k-pair 0..127
        int n = p & 63;
        int k = kp * 2;
        unsigned lo = f2bf_rne(W[k * F_OUT + n]);
        unsigned hi = f2bf_rne(W[(k + 1) * F_OUT + n]);
        Wf[((k >> 3) * 64 + n) * 4 + ((k & 7) >> 1)] = lo | (hi << 16);
    }
    __syncthreads();

    const int wave = threadIdx.x >> 6;
    const int lane = threadIdx.x & 63;
    const int q = lane >> 4;
    const int c = lane & 15;
    const int n0 = blockIdx.x * 128 + wave * 16;
    const int r = min(n0 + c, N - 1);
    const float* p0 = x + (size_t)r * F_IN + q * 8;

    f32x4 acc[4] = {};
#pragma unroll
    for (int s = 0; s < 8; s++) {
        float4 a0 = *(const float4*)(p0 + s * 32);
        float4 a1 = *(const float4*)(p0 + s * 32 + 4);
        short8 ah = pack_hi(a0, a1), al = pack_lo(a0, a1);
#pragma unroll
        for (int t = 0; t < 4; t++) {
            short8 bh = *(const short8*)&Wf[((s * 4 + q) * 64 + t * 16 + c) * 4];
            acc[t] = __builtin_amdgcn_mfma_f32_16x16x32_bf16(ah, bh, acc[t], 0, 0, 0);
            acc[t] = __builtin_amdgcn_mfma_f32_16x16x32_bf16(al, bh, acc[t], 0, 0, 0);
        }
    }

    // D layout: col = t*16 + c (feature), row = q*4 + rr (node). Pack col
    // pairs via shfl_xor(1), store bf16x2.
#pragma unroll
    for (int rr = 0; rr < 4; rr++) {
        int node = n0 + q * 4 + rr;
        float dv = dinv[min(node, N - 1)];
#pragma unroll
        for (int t = 0; t < 4; t++) {
            float v = acc[t][rr] * dv;
            float o = __shfl_xor(v, 1, 64);
            if (node < N && !(lane & 1)) {
                unsigned pk = (unsigned)f2bf_rne(v) | ((unsigned)f2bf_rne(o) << 16);
                gu[(size_t)node * 32 + t * 8 + (c >> 1)] = pk;
            }
        }
    }
}

// ---------------------------------------------------------------------------
// K5: gather + fused epilogue. Wave = node; 4 quads x 2-deep unroll = 8 edges
// in flight; per-edge each quad's 16 lanes read one 128B bf16 row of g.
// ---------------------------------------------------------------------------
__global__ __launch_bounds__(256) void gather_epilogue(const int* __restrict__ csr,
                                                       const int* __restrict__ rowOff,
                                                       const unsigned* __restrict__ g32,
                                                       const float* __restrict__ dinv,
                                                       const float* __restrict__ bias,
                                                       float* __restrict__ out, int N) {
    int n = blockIdx.x * 4 + (threadIdx.x >> 6);
    if (n >= N) return;
    const int lane = threadIdx.x & 63;
    const int q = lane >> 4;
    const int h = lane & 15;
    const int start = rowOff[n], end = rowOff[n + 1];
    const uint2* g2 = (const uint2*)g32;

    float4 acc = {0, 0, 0, 0}, acc2 = {0, 0, 0, 0};
    int i = start + q;
    for (; i + 4 < end; i += 8) {
        int s0 = csr[i], s1 = csr[i + 4];
        uint2 u0 = g2[(size_t)s0 * 16 + h];
        uint2 u1 = g2[(size_t)s1 * 16 + h];
        acc.x += bf_lo(u0.x); acc.y += bf_hi(u0.x);
        acc.z += bf_lo(u0.y); acc.w += bf_hi(u0.y);
        acc2.x += bf_lo(u1.x); acc2.y += bf_hi(u1.x);
        acc2.z += bf_lo(u1.y); acc2.w += bf_hi(u1.y);
    }
    if (i < end) {
        int s0 = csr[i];
        uint2 u0 = g2[(size_t)s0 * 16 + h];
        acc.x += bf_lo(u0.x); acc.y += bf_hi(u0.x);
        acc.z += bf_lo(u0.y); acc.w += bf_hi(u0.y);
    }
    acc.x += acc2.x; acc.y += acc2.y; acc.z += acc2.z; acc.w += acc2.w;
    acc.x += __shfl_xor(acc.x, 16, 64);
    acc.y += __shfl_xor(acc.y, 16, 64);
    acc.z += __shfl_xor(acc.z, 16, 64);
    acc.w += __shfl_xor(acc.w, 16, 64);
    acc.x += __shfl_xor(acc.x, 32, 64);
    acc.y += __shfl_xor(acc.y, 32, 64);
    acc.z += __shfl_xor(acc.z, 32, 64);
    acc.w += __shfl_xor(acc.w, 32, 64);
    if (q == 0) {
        uint2 us = g2[(size_t)n * 16 + h];  // self loop
        float dv = dinv[n];
        int c4 = h << 2;
        float4 bb = *(const float4*)&bias[c4];
        float4 r;
        r.x = fmaxf(fmaf(dv, acc.x + bf_lo(us.x), bb.x), 0.0f);
        r.y = fmaxf(fmaf(dv, acc.y + bf_hi(us.x), bb.y), 0.0f);
        r.z = fmaxf(fmaf(dv, acc.z + bf_lo(us.y), bb.z), 0.0f);
        r.w = fmaxf(fmaf(dv, acc.w + bf_hi(us.y), bb.w), 0.0f);
        *(float4*)&out[(size_t)n * F_OUT + c4] = r;
    }
}

extern "C" void kernel_launch(void* const* d_in, const int* in_sizes, int n_in,
                              void* d_out, int out_size, void* d_ws, size_t ws_size,
                              hipStream_t stream) {
    const float* x = (const float*)d_in[0];
    const int* adj = (const int*)d_in[1];
    const float* W = (const float*)d_in[2];
    const float* b = (const float*)d_in[3];
    float* out = (float*)d_out;

    const int N = in_sizes[0] / F_IN;  // 50000
    const int E = in_sizes[1] / 2;     // 800000
    const int nbins = (N + 1023) >> SHIFT;               // 49 (<= NBINS_MAX)
    const int avg = (E + nbins - 1) / nbins;
    const int maxBin = ((avg + (avg >> 2)) + 63) & ~63;  // 1.25x headroom

    // ws: rowOff(N+1) | dinv(N) | curg(N) | cursorRel(64) | csr(E) |
    //     region { staging (nbins*maxBin uint2) aliased with g (bf16) }
    char* ws = (char*)d_ws;
    size_t segN = (((size_t)(N + 1) * 4) + 255) & ~(size_t)255;
    int* rowOff = (int*)ws;
    float* dinv = (float*)(ws + segN);
    int* curg = (int*)(ws + 2 * segN);
    int* cursorRel = (int*)(ws + 3 * segN);
    int* csr = (int*)(ws + 3 * segN + 256);
    size_t csrBytes = (((size_t)E * 4) + 255) & ~(size_t)255;
    char* region = ws + 3 * segN + 256 + csrBytes;
    uint2* staging = (uint2*)region;
    unsigned* g16 = (unsigned*)region;  // aliases staging (dead after scatter)

    hipMemsetAsync(cursorRel, 0, 256, stream);

    const int P = 8;
    bin_pass1<<<(E + BATCH - 1) / BATCH, 256, 0, stream>>>(adj, staging, cursorRel,
                                                           E, nbins, maxBin);
    scan_bins<<<nbins, 256, 0, stream>>>(staging, cursorRel, rowOff, curg, dinv,
                                         N, E, maxBin, nbins);
    scatter_csr<<<nbins * P, 256, 0, stream>>>(staging, cursorRel, curg, csr, maxBin, P);
    gemm_mfma<<<(N + 127) / 128, 512, 0, stream>>>(x, W, dinv, g16, N);
    gather_epilogue<<<(N + 3) / 4, 256, 0, stream>>>(csr, rowOff, g16, dinv, b, out, N);
}

// Round 6
// 200.417 us; speedup vs baseline: 1.7706x; 1.7706x over previous
//
#include <hip/hip_runtime.h>

#define F_IN 256
#define F_OUT 64
#define SHIFT 10          // bin width 1024 nodes
#define NBINS_MAX 64      // supports N <= 65536
#define BATCH 1024        // edges per block in pass1 (4 per thread)

typedef __attribute__((ext_vector_type(8))) short short8;
typedef __attribute__((ext_vector_type(4))) float f32x4;

// ---------------------------------------------------------------------------
// bf16 helpers. hi = truncated bf16, lo = RNE bf16 of exact residual.
// ---------------------------------------------------------------------------
__device__ inline unsigned short f2bf_rne(float f) {
    unsigned u = __float_as_uint(f);
    return (unsigned short)((u + 0x7fffu + ((u >> 16) & 1u)) >> 16);
}
__device__ inline float trunc_res(float f) {
    return f - __uint_as_float(__float_as_uint(f) & 0xFFFF0000u);
}
__device__ inline float bf_lo(unsigned u) { return __uint_as_float(u << 16); }
__device__ inline float bf_hi(unsigned u) { return __uint_as_float(u & 0xFFFF0000u); }
__device__ inline short8 pack_hi(float4 a, float4 b) {
    union { unsigned u[4]; short8 s; } r;
    r.u[0] = (__float_as_uint(a.x) >> 16) | (__float_as_uint(a.y) & 0xFFFF0000u);
    r.u[1] = (__float_as_uint(a.z) >> 16) | (__float_as_uint(a.w) & 0xFFFF0000u);
    r.u[2] = (__float_as_uint(b.x) >> 16) | (__float_as_uint(b.y) & 0xFFFF0000u);
    r.u[3] = (__float_as_uint(b.z) >> 16) | (__float_as_uint(b.w) & 0xFFFF0000u);
    return r.s;
}
__device__ inline short8 pack_lo(float4 a, float4 b) {
    union { unsigned u[4]; short8 s; } r;
    r.u[0] = f2bf_rne(trunc_res(a.x)) | ((unsigned)f2bf_rne(trunc_res(a.y)) << 16);
    r.u[1] = f2bf_rne(trunc_res(a.z)) | ((unsigned)f2bf_rne(trunc_res(a.w)) << 16);
    r.u[2] = f2bf_rne(trunc_res(b.x)) | ((unsigned)f2bf_rne(trunc_res(b.y)) << 16);
    r.u[3] = f2bf_rne(trunc_res(b.z)) | ((unsigned)f2bf_rne(trunc_res(b.w)) << 16);
    return r.s;
}

// ---------------------------------------------------------------------------
// K1: bufferless block binning. R5's 48KB LDS entry-buffer capped occupancy
// at ~5 waves/CU -> 174us of pure stall; measured WRITE_SIZE (=footprint)
// proved L2 already merges bin-window writes, so the buffer was pointless.
// Now: LDS histogram (slot = atomicAdd(cnt[bin])) -> one global atomic per
// bin -> direct store at staging[bin*maxBin + base[bin] + slot]. A block's
// slots are dense within each bin window => full-line L2 writeback.
// LDS = 512B -> occupancy ~wave-limit; 4 independent edges/thread.
// ---------------------------------------------------------------------------
__global__ __launch_bounds__(256) void bin_pass1(const int* __restrict__ adj,
                                                 uint2* __restrict__ staging,
                                                 int* __restrict__ cursorRel,
                                                 int E, int nbins, int maxBin) {
    __shared__ int cnt[NBINS_MAX];
    __shared__ int base[NBINS_MAX];
    const int tid = threadIdx.x;
    if (tid < NBINS_MAX) cnt[tid] = 0;
    __syncthreads();

    const int e0 = blockIdx.x * BATCH;
    const int e1 = min(e0 + BATCH, E);
    const int e = e0 + tid * 4;
    const bool al4 = ((E & 3) == 0);

    int ss[4], dd[4], slot[4];
    int nv = 0;
    if (e < e1) {
        if (al4 && e + 4 <= e1) {
            int4 s4 = *(const int4*)&adj[e];
            int4 d4 = *(const int4*)&adj[E + e];
            ss[0] = s4.x; ss[1] = s4.y; ss[2] = s4.z; ss[3] = s4.w;
            dd[0] = d4.x; dd[1] = d4.y; dd[2] = d4.z; dd[3] = d4.w;
            nv = 4;
        } else {
            for (int k = 0; k < 4 && e + k < e1; k++) {
                ss[k] = adj[e + k];
                dd[k] = adj[E + e + k];
                nv++;
            }
        }
    }
#pragma unroll
    for (int j = 0; j < 4; j++) {
        if (j < nv) slot[j] = atomicAdd(&cnt[dd[j] >> SHIFT], 1);
    }
    __syncthreads();
    if (tid < nbins) base[tid] = atomicAdd(&cursorRel[tid], cnt[tid]);
    __syncthreads();
#pragma unroll
    for (int j = 0; j < 4; j++) {
        if (j < nv) {
            int b = dd[j] >> SHIFT;
            int pos = base[b] + slot[j];
            if (pos < maxBin)
                staging[(size_t)b * maxBin + pos] = make_uint2((unsigned)ss[j], (unsigned)dd[j]);
        }
    }
}

// ---------------------------------------------------------------------------
// K2: one block per bin. Histogram staged dsts -> block scan -> write rowOff
// (segment starts), curg (scatter cursors, = rowOff copy), dinv.
// ---------------------------------------------------------------------------
__global__ __launch_bounds__(256) void scan_bins(const uint2* __restrict__ staging,
                                                 const int* __restrict__ cursorRel,
                                                 int* __restrict__ rowOff,
                                                 int* __restrict__ curg,
                                                 float* __restrict__ dinv,
                                                 int N, int E, int maxBin, int nbins) {
    __shared__ int deg[1024];
    __shared__ int cur[1024];
    __shared__ int wsum[4];
    __shared__ int baseSh;
    const int b = blockIdx.x;
    const int tid = threadIdx.x;
    const int nb0 = b << SHIFT;
    const int nn = min(1024, N - nb0);
    const int segCnt = min(cursorRel[b], maxBin);
    const uint2* seg = staging + (size_t)b * maxBin;

    if (tid < 64) {  // base = edges in bins before this one
        int v = (tid < b) ? min(cursorRel[tid], maxBin) : 0;
        for (int d = 1; d < 64; d <<= 1) v += __shfl_xor(v, d, 64);
        if (tid == 0) baseSh = v;
    }
    for (int j = tid; j < 1024; j += 256) deg[j] = 0;
    __syncthreads();
    const int base = baseSh;

    for (int i = tid; i < segCnt; i += 256) {
        uint2 e = seg[i];
        atomicAdd(&deg[(int)e.y - nb0], 1);
    }
    __syncthreads();

    const int j0 = tid * 4;
    const int d0 = deg[j0], d1 = deg[j0 + 1], d2 = deg[j0 + 2], d3 = deg[j0 + 3];
    const int s = d0 + d1 + d2 + d3;
    const int lane = tid & 63, w = tid >> 6;
    int incl = s;
    for (int d = 1; d < 64; d <<= 1) {
        int t = __shfl_up(incl, d, 64);
        if (lane >= d) incl += t;
    }
    if (lane == 63) wsum[w] = incl;
    __syncthreads();
    int wofs = 0;
    for (int k = 0; k < 3; k++) if (k < w) wofs += wsum[k];
    int ex = base + wofs + incl - s;
    cur[j0] = ex;
    cur[j0 + 1] = ex + d0;
    cur[j0 + 2] = ex + d0 + d1;
    cur[j0 + 3] = ex + d0 + d1 + d2;
    __syncthreads();

    for (int j = tid; j < nn; j += 256) {
        int v = cur[j];
        rowOff[nb0 + j] = v;
        curg[nb0 + j] = v;
        dinv[nb0 + j] = rsqrtf((float)deg[j] + 1.0f);
    }
    if (b == nbins - 1 && tid == 0) rowOff[N] = E;
}

// ---------------------------------------------------------------------------
// K3: parallel scatter, 8 blocks/bin. Global atomics on curg; csr writes stay
// within each bin's ~65KB window (L2-hot) -> writeback ~ footprint.
// ---------------------------------------------------------------------------
__global__ __launch_bounds__(256) void scatter_csr(const uint2* __restrict__ staging,
                                                   const int* __restrict__ cursorRel,
                                                   int* __restrict__ curg,
                                                   int* __restrict__ csr,
                                                   int maxBin, int P) {
    const int b = blockIdx.x / P;
    const int p = blockIdx.x - b * P;
    const int segCnt = min(cursorRel[b], maxBin);
    const uint2* seg = staging + (size_t)b * maxBin;
    for (int i = p * 256 + threadIdx.x; i < segCnt; i += P * 256) {
        uint2 e = seg[i];
        int pos = atomicAdd(&curg[(int)e.y], 1);
        csr[pos] = (int)e.x;
    }
}

// ---------------------------------------------------------------------------
// K4: g(bf16) = dinv[n] * (x @ W) via bf16 MFMA, x = hi+lo split.
// 512-thread blocks, 16 nodes/wave, W staged once per 128 nodes into
// B-fragment-major LDS (u32-packed pairs).
// ---------------------------------------------------------------------------
__global__ __launch_bounds__(512, 4) void gemm_mfma(const float* __restrict__ x,
                                                    const float* __restrict__ W,
                                                    const float* __restrict__ dinv,
                                                    unsigned* __restrict__ gu, int N) {
    __shared__ unsigned Wf[32 * 64 * 4];  // 32 KB: [kchunk][n][4 x u32(bf16x2)]
    for (int p = threadIdx.x; p < (F_IN / 2) * F_OUT; p += 512) {
        int kp = p >> 6;  // k-pair 0..127
        int n = p & 63;
        int k = kp * 2;
        unsigned lo = f2bf_rne(W[k * F_OUT + n]);
        unsigned hi = f2bf_rne(W[(k + 1) * F_OUT + n]);
        Wf[((k >> 3) * 64 + n) * 4 + ((k & 7) >> 1)] = lo | (hi << 16);
    }
    __syncthreads();

    const int wave = threadIdx.x >> 6;
    const int lane = threadIdx.x & 63;
    const int q = lane >> 4;
    const int c = lane & 15;
    const int n0 = blockIdx.x * 128 + wave * 16;
    const int r = min(n0 + c, N - 1);
    const float* p0 = x + (size_t)r * F_IN + q * 8;

    f32x4 acc[4] = {};
#pragma unroll
    for (int s = 0; s < 8; s++) {
        float4 a0 = *(const float4*)(p0 + s * 32);
        float4 a1 = *(const float4*)(p0 + s * 32 + 4);
        short8 ah = pack_hi(a0, a1), al = pack_lo(a0, a1);
#pragma unroll
        for (int t = 0; t < 4; t++) {
            short8 bh = *(const short8*)&Wf[((s * 4 + q) * 64 + t * 16 + c) * 4];
            acc[t] = __builtin_amdgcn_mfma_f32_16x16x32_bf16(ah, bh, acc[t], 0, 0, 0);
            acc[t] = __builtin_amdgcn_mfma_f32_16x16x32_bf16(al, bh, acc[t], 0, 0, 0);
        }
    }

    // D layout: col = t*16 + c (feature), row = q*4 + rr (node). Pack col
    // pairs via shfl_xor(1), store bf16x2.
#pragma unroll
    for (int rr = 0; rr < 4; rr++) {
        int node = n0 + q * 4 + rr;
        float dv = dinv[min(node, N - 1)];
#pragma unroll
        for (int t = 0; t < 4; t++) {
            float v = acc[t][rr] * dv;
            float o = __shfl_xor(v, 1, 64);
            if (node < N && !(lane & 1)) {
                unsigned pk = (unsigned)f2bf_rne(v) | ((unsigned)f2bf_rne(o) << 16);
                gu[(size_t)node * 32 + t * 8 + (c >> 1)] = pk;
            }
        }
    }
}

// ---------------------------------------------------------------------------
// K5: gather + fused epilogue. Wave = node; 4 quads x 2-deep unroll = 8 edges
// in flight; per-edge each quad's 16 lanes read one 128B bf16 row of g.
// ---------------------------------------------------------------------------
__global__ __launch_bounds__(256) void gather_epilogue(const int* __restrict__ csr,
                                                       const int* __restrict__ rowOff,
                                                       const unsigned* __restrict__ g32,
                                                       const float* __restrict__ dinv,
                                                       const float* __restrict__ bias,
                                                       float* __restrict__ out, int N) {
    int n = blockIdx.x * 4 + (threadIdx.x >> 6);
    if (n >= N) return;
    const int lane = threadIdx.x & 63;
    const int q = lane >> 4;
    const int h = lane & 15;
    const int start = rowOff[n], end = rowOff[n + 1];
    const uint2* g2 = (const uint2*)g32;

    float4 acc = {0, 0, 0, 0}, acc2 = {0, 0, 0, 0};
    int i = start + q;
    for (; i + 4 < end; i += 8) {
        int s0 = csr[i], s1 = csr[i + 4];
        uint2 u0 = g2[(size_t)s0 * 16 + h];
        uint2 u1 = g2[(size_t)s1 * 16 + h];
        acc.x += bf_lo(u0.x); acc.y += bf_hi(u0.x);
        acc.z += bf_lo(u0.y); acc.w += bf_hi(u0.y);
        acc2.x += bf_lo(u1.x); acc2.y += bf_hi(u1.x);
        acc2.z += bf_lo(u1.y); acc2.w += bf_hi(u1.y);
    }
    if (i < end) {
        int s0 = csr[i];
        uint2 u0 = g2[(size_t)s0 * 16 + h];
        acc.x += bf_lo(u0.x); acc.y += bf_hi(u0.x);
        acc.z += bf_lo(u0.y); acc.w += bf_hi(u0.y);
    }
    acc.x += acc2.x; acc.y += acc2.y; acc.z += acc2.z; acc.w += acc2.w;
    acc.x += __shfl_xor(acc.x, 16, 64);
    acc.y += __shfl_xor(acc.y, 16, 64);
    acc.z += __shfl_xor(acc.z, 16, 64);
    acc.w += __shfl_xor(acc.w, 16, 64);
    acc.x += __shfl_xor(acc.x, 32, 64);
    acc.y += __shfl_xor(acc.y, 32, 64);
    acc.z += __shfl_xor(acc.z, 32, 64);
    acc.w += __shfl_xor(acc.w, 32, 64);
    if (q == 0) {
        uint2 us = g2[(size_t)n * 16 + h];  // self loop
        float dv = dinv[n];
        int c4 = h << 2;
        float4 bb = *(const float4*)&bias[c4];
        float4 r;
        r.x = fmaxf(fmaf(dv, acc.x + bf_lo(us.x), bb.x), 0.0f);
        r.y = fmaxf(fmaf(dv, acc.y + bf_hi(us.x), bb.y), 0.0f);
        r.z = fmaxf(fmaf(dv, acc.z + bf_lo(us.y), bb.z), 0.0f);
        r.w = fmaxf(fmaf(dv, acc.w + bf_hi(us.y), bb.w), 0.0f);
        *(float4*)&out[(size_t)n * F_OUT + c4] = r;
    }
}

extern "C" void kernel_launch(void* const* d_in, const int* in_sizes, int n_in,
                              void* d_out, int out_size, void* d_ws, size_t ws_size,
                              hipStream_t stream) {
    const float* x = (const float*)d_in[0];
    const int* adj = (const int*)d_in[1];
    const float* W = (const float*)d_in[2];
    const float* b = (const float*)d_in[3];
    float* out = (float*)d_out;

    const int N = in_sizes[0] / F_IN;  // 50000
    const int E = in_sizes[1] / 2;     // 800000
    const int nbins = (N + 1023) >> SHIFT;               // 49 (<= NBINS_MAX)
    const int avg = (E + nbins - 1) / nbins;
    const int maxBin = ((avg + (avg >> 2)) + 63) & ~63;  // 1.25x headroom

    // ws: rowOff(N+1) | dinv(N) | curg(N) | cursorRel(64) | csr(E) |
    //     region { staging (nbins*maxBin uint2) aliased with g (bf16) }
    char* ws = (char*)d_ws;
    size_t segN = (((size_t)(N + 1) * 4) + 255) & ~(size_t)255;
    int* rowOff = (int*)ws;
    float* dinv = (float*)(ws + segN);
    int* curg = (int*)(ws + 2 * segN);
    int* cursorRel = (int*)(ws + 3 * segN);
    int* csr = (int*)(ws + 3 * segN + 256);
    size_t csrBytes = (((size_t)E * 4) + 255) & ~(size_t)255;
    char* region = ws + 3 * segN + 256 + csrBytes;
    uint2* staging = (uint2*)region;
    unsigned* g16 = (unsigned*)region;  // aliases staging (dead after scatter)

    hipMemsetAsync(cursorRel, 0, 256, stream);

    const int P = 8;
    bin_pass1<<<(E + BATCH - 1) / BATCH, 256, 0, stream>>>(adj, staging, cursorRel,
                                                           E, nbins, maxBin);
    scan_bins<<<nbins, 256, 0, stream>>>(staging, cursorRel, rowOff, curg, dinv,
                                         N, E, maxBin, nbins);
    scatter_csr<<<nbins * P, 256, 0, stream>>>(staging, cursorRel, curg, csr, maxBin, P);
    gemm_mfma<<<(N + 127) / 128, 512, 0, stream>>>(x, W, dinv, g16, N);
    gather_epilogue<<<(N + 3) / 4, 256, 0, stream>>>(csr, rowOff, g16, dinv, b, out, N);
}